// Round 4
// baseline (20433.263 us; speedup 1.0000x reference)
//
#include <hip/hip_runtime.h>
#include <stdint.h>

#define B_  256
#define S_  512
#define D_  64
#define H_  256
#define G3_ 768

typedef __attribute__((ext_vector_type(8))) short s8v;   // 8 bf16 (4 VGPRs)
typedef __attribute__((ext_vector_type(4))) float f4v;   // MFMA accumulator

__device__ __forceinline__ unsigned short f2bf(float x) {  // RNE
  unsigned u = __float_as_uint(x);
  unsigned r = (u + 0x7fffu + ((u >> 16) & 1u)) >> 16;
  return (unsigned short)r;
}
__device__ __forceinline__ float bf2f(unsigned short s) {
  return __uint_as_float(((unsigned)s) << 16);
}
__device__ __forceinline__ float sigm(float x) {
  return __builtin_amdgcn_rcpf(1.f + __expf(-x));
}
__device__ __forceinline__ float tanh_f(float x) {
  return 1.f - 2.f * __builtin_amdgcn_rcpf(1.f + __expf(2.f * x));
}

// ---------------------------------------------------------------------------
// MFMA bf16-split input GEMM (unchanged from round 2, bias ptr = bias2).
// ---------------------------------------------------------------------------
__global__ __launch_bounds__(256) void gemm_mfma(
    const float* __restrict__ A, const float* __restrict__ W,
    const float* __restrict__ bias, float* __restrict__ C,
    int K, int chsh, int t0)
{
  const int g0 = blockIdx.x * 64;
  const int r0 = blockIdx.y * 64;
  const int tid = threadIdx.x;
  const int w = tid >> 6, l = tid & 63;
  const int fr = l & 15, fq = l >> 4;

  __shared__ unsigned short Ah[64][40], Al[64][40];
  __shared__ unsigned short Wh[64][40], Wl[64][40];

  f4v acc[4] = {};

  const int row = tid >> 2, q = tid & 3;
  const int CHm1 = (1 << chsh) - 1;
  const int r = r0 + row;
  const int rg = ((r >> chsh) * S_) + t0 + (r & CHm1);
  const float* ap = A + (size_t)rg * K + q * 8;
  const float* wp = W + (size_t)(g0 + row) * K + q * 8;

  for (int k0 = 0; k0 < K; k0 += 32) {
    float4 a0 = *(const float4*)(ap + k0);
    float4 a1 = *(const float4*)(ap + k0 + 4);
    float4 w0 = *(const float4*)(wp + k0);
    float4 w1 = *(const float4*)(wp + k0 + 4);
    __syncthreads();
    float av[8] = {a0.x,a0.y,a0.z,a0.w,a1.x,a1.y,a1.z,a1.w};
    float wv[8] = {w0.x,w0.y,w0.z,w0.w,w1.x,w1.y,w1.z,w1.w};
    unsigned short ah[8], al_[8], wh[8], wl_[8];
    #pragma unroll
    for (int i = 0; i < 8; ++i) {
      ah[i]  = f2bf(av[i]);  al_[i] = f2bf(av[i] - bf2f(ah[i]));
      wh[i]  = f2bf(wv[i]);  wl_[i] = f2bf(wv[i] - bf2f(wh[i]));
    }
    *(s8v*)&Ah[row][q*8] = *(s8v*)ah;  *(s8v*)&Al[row][q*8] = *(s8v*)al_;
    *(s8v*)&Wh[row][q*8] = *(s8v*)wh;  *(s8v*)&Wl[row][q*8] = *(s8v*)wl_;
    __syncthreads();

    s8v a_hi = *(const s8v*)&Ah[w*16 + fr][fq*8];
    s8v a_lo = *(const s8v*)&Al[w*16 + fr][fq*8];
    #pragma unroll
    for (int c = 0; c < 4; ++c) {
      s8v b_hi = *(const s8v*)&Wh[c*16 + fr][fq*8];
      s8v b_lo = *(const s8v*)&Wl[c*16 + fr][fq*8];
      acc[c] = __builtin_amdgcn_mfma_f32_16x16x32_bf16(a_hi, b_hi, acc[c], 0, 0, 0);
      acc[c] = __builtin_amdgcn_mfma_f32_16x16x32_bf16(a_lo, b_hi, acc[c], 0, 0, 0);
      acc[c] = __builtin_amdgcn_mfma_f32_16x16x32_bf16(a_hi, b_lo, acc[c], 0, 0, 0);
    }
  }

  const int orow = r0 + w * 16 + fq * 4;
  #pragma unroll
  for (int c = 0; c < 4; ++c) {
    const float bi = bias[g0 + c * 16 + fr];
    #pragma unroll
    for (int i = 0; i < 4; ++i) {
      float v = acc[c][i] + bi;
      __builtin_nontemporal_store(v, &C[(size_t)(orow + i) * G3_ + g0 + c * 16 + fr]);
    }
  }
}

// ---------------------------------------------------------------------------
// Pack W_hh into MFMA B-fragment order, split hi/lo bf16.
// Layout: frag f = (gti*8 + kc), element [lane][8]; tile gti covers W rows
// [16gti,16gti+16), k-chunk kc covers k [32kc,32kc+32).
// Lane l: row 16gti+(l&15), k 32kc+(l>>4)*8 .. +8  (verified frag pattern).
// ---------------------------------------------------------------------------
__global__ __launch_bounds__(64) void pack_whh(
    const float* __restrict__ Whh, unsigned short* __restrict__ Whp,
    unsigned short* __restrict__ Wlp)
{
  const int gti = blockIdx.x, kc = blockIdx.y, lane = threadIdx.x;
  const int row = gti * 16 + (lane & 15);
  const int k0  = kc * 32 + (lane >> 4) * 8;
  const float* src = &Whh[(size_t)row * H_ + k0];
  unsigned short hi8[8], lo8[8];
  #pragma unroll
  for (int s = 0; s < 8; ++s) {
    float f = src[s];
    unsigned short hi = f2bf(f);
    hi8[s] = hi;
    lo8[s] = f2bf(f - bf2f(hi));
  }
  const size_t o = ((size_t)(gti * 8 + kc) * 64 + lane) * 8;
  *(s8v*)&Whp[o] = *(s8v*)hi8;
  *(s8v*)&Wlp[o] = *(s8v*)lo8;
}

// bias2[g] = b_ih[g] + (g<512 ? b_hh[g] : 0)   (fold r/z hidden bias into gx)
__global__ __launch_bounds__(768) void bias2_k(
    const float* __restrict__ bih, const float* __restrict__ bhh,
    float* __restrict__ bias2)
{
  int g = threadIdx.x;
  bias2[g] = bih[g] + (g < 512 ? bhh[g] : 0.f);
}

// ---------------------------------------------------------------------------
// MFMA GRU scan. 16 WGs x 512 thr (8 waves). WG: 16 batches, all 768 gates.
// Wave w owns units [32w,32w+32): gate tiles {2w,2w+1} (r), {16+2w,+1} (z),
// {32+2w,+1} (n). Wh-hi: r/z tiles in VGPRs (128), n tiles in LDS (128KB).
// Wh-lo streamed from L2 per step (384KB/WG, overlapped with MFMA).
// h in wave registers (D-layout); rebuilt into LDS A-frags (hi+lo) each step
// via shfl. acc = mfma(Wh_hi,a_hi)+mfma(Wh_hi,a_lo)+mfma(Wl,a_hi).
// D layout: row=(l>>4)*4+i -> gate-local, col=l&15 -> batch.
// ---------------------------------------------------------------------------
__global__ __launch_bounds__(512, 2) void gru_scan(
    const float* __restrict__ gx, const unsigned short* __restrict__ Whp,
    const unsigned short* __restrict__ Wlp, const float* __restrict__ bhh,
    float* __restrict__ hbuf, float* __restrict__ y,
    int CH, int t0c, int last)
{
  const int bid = blockIdx.x;          // 16
  const int b0  = bid * 16;
  const int tid = threadIdx.x;
  const int wid = tid >> 6, lane = tid & 63;
  const int bb = lane & 15;            // batch-local
  const int bq = lane >> 4;            // gate quad

  extern __shared__ unsigned short lds_[];
  unsigned short* WhN = lds_;                 // [8 w][2 tt][8 kc][512] = 128KB
  unsigned short* Ahh = lds_ + 65536;         // [8 kc][512] = 8KB
  unsigned short* Ahl = Ahh + 4096;           // 8KB

  const s8v* WhpV = (const s8v*)Whp;
  const s8v* WlpV = (const s8v*)Wlp;

  // ---- resident Wh-hi: r,z tiles in regs; n tiles staged to LDS ----
  s8v whr[4][8];
  #pragma unroll
  for (int tt = 0; tt < 4; ++tt) {
    const int gti = (tt < 2) ? (2 * wid + tt) : (16 + 2 * wid + (tt - 2));
    #pragma unroll
    for (int kc = 0; kc < 8; ++kc)
      whr[tt][kc] = WhpV[(gti * 8 + kc) * 64 + lane];
  }
  #pragma unroll
  for (int tt = 0; tt < 2; ++tt) {
    const int gti = 32 + 2 * wid + tt;
    #pragma unroll
    for (int kc = 0; kc < 8; ++kc) {
      s8v v = WhpV[(gti * 8 + kc) * 64 + lane];
      *(s8v*)&WhN[(((wid * 2 + tt) * 8) + kc) * 512 + lane * 8] = v;
    }
  }

  // ---- h registers + n-gate hidden bias ----
  float hreg[2][4];
  float bhn_r[2][4];
  #pragma unroll
  for (int p = 0; p < 2; ++p)
    #pragma unroll
    for (int i = 0; i < 4; ++i) {
      const int u = 32 * wid + 16 * p + 4 * bq + i;
      hreg[p][i]  = (t0c == 0) ? 0.f : hbuf[(size_t)(b0 + bb) * H_ + u];
      bhn_r[p][i] = bhh[2 * H_ + u];
    }

  for (int t = 0; t < CH; ++t) {
    // gx prefetch (latency hidden under A-build + MFMA passes)
    float xg[3][2][4];
    {
      const float* gb = gx + ((size_t)(b0 + bb) * CH + t) * G3_;
      #pragma unroll
      for (int p = 0; p < 2; ++p)
        #pragma unroll
        for (int i = 0; i < 4; ++i) {
          const int u = 32 * wid + 16 * p + 4 * bq + i;
          xg[0][p][i] = gb[u];
          xg[1][p][i] = gb[H_ + u];
          xg[2][p][i] = gb[2 * H_ + u];
        }
    }

    __syncthreads();   // step t-1 A-frag reads done (and WhN staged, t=0)

    // ---- build A-frags (hi/lo) for k-chunk w from hreg via shfl ----
    {
      const int uc = lane >> 4;
      unsigned short hh8[8], hl8[8];
      #pragma unroll
      for (int s = 0; s < 8; ++s) {
        const int q   = 2 * (uc & 1) + (s >> 2);
        const int src = bb | (q << 4);
        float v0 = __shfl(hreg[0][s & 3], src, 64);
        float v1 = __shfl(hreg[1][s & 3], src, 64);
        float v  = (uc >> 1) ? v1 : v0;
        unsigned short hi = f2bf(v);
        hh8[s] = hi;
        hl8[s] = f2bf(v - bf2f(hi));
      }
      *(s8v*)&Ahh[wid * 512 + lane * 8] = *(s8v*)hh8;
      *(s8v*)&Ahl[wid * 512 + lane * 8] = *(s8v*)hl8;
    }
    __syncthreads();

    // ---- pass A: r,z gates (reg-resident Wh-hi) ----
    f4v accA[4] = {};
    {
      s8v wlb[2][4];
      #pragma unroll
      for (int tt = 0; tt < 4; ++tt) {
        const int gti = (tt < 2) ? (2 * wid + tt) : (16 + 2 * wid + (tt - 2));
        wlb[0][tt] = WlpV[(gti * 8 + 0) * 64 + lane];
      }
      #pragma unroll
      for (int kc = 0; kc < 8; ++kc) {
        if (kc < 7) {
          #pragma unroll
          for (int tt = 0; tt < 4; ++tt) {
            const int gti = (tt < 2) ? (2 * wid + tt) : (16 + 2 * wid + (tt - 2));
            wlb[(kc + 1) & 1][tt] = WlpV[(gti * 8 + kc + 1) * 64 + lane];
          }
        }
        s8v ahh = *(const s8v*)&Ahh[kc * 512 + lane * 8];
        s8v ahl = *(const s8v*)&Ahl[kc * 512 + lane * 8];
        #pragma unroll
        for (int tt = 0; tt < 4; ++tt) {
          accA[tt] = __builtin_amdgcn_mfma_f32_16x16x32_bf16(whr[tt][kc], ahh, accA[tt], 0, 0, 0);
          accA[tt] = __builtin_amdgcn_mfma_f32_16x16x32_bf16(whr[tt][kc], ahl, accA[tt], 0, 0, 0);
          accA[tt] = __builtin_amdgcn_mfma_f32_16x16x32_bf16(wlb[kc & 1][tt], ahh, accA[tt], 0, 0, 0);
        }
      }
    }

    // ---- pass B: n gates (LDS-resident Wh-hi) ----
    f4v accB[2] = {};
    {
      s8v wnb[2][2];
      #pragma unroll
      for (int tt = 0; tt < 2; ++tt)
        wnb[0][tt] = WlpV[((32 + 2 * wid + tt) * 8 + 0) * 64 + lane];
      #pragma unroll
      for (int kc = 0; kc < 8; ++kc) {
        if (kc < 7) {
          #pragma unroll
          for (int tt = 0; tt < 2; ++tt)
            wnb[(kc + 1) & 1][tt] = WlpV[((32 + 2 * wid + tt) * 8 + kc + 1) * 64 + lane];
        }
        s8v ahh = *(const s8v*)&Ahh[kc * 512 + lane * 8];
        s8v ahl = *(const s8v*)&Ahl[kc * 512 + lane * 8];
        #pragma unroll
        for (int tt = 0; tt < 2; ++tt) {
          s8v wh = *(const s8v*)&WhN[(((wid * 2 + tt) * 8) + kc) * 512 + lane * 8];
          accB[tt] = __builtin_amdgcn_mfma_f32_16x16x32_bf16(wh, ahh, accB[tt], 0, 0, 0);
          accB[tt] = __builtin_amdgcn_mfma_f32_16x16x32_bf16(wh, ahl, accB[tt], 0, 0, 0);
          accB[tt] = __builtin_amdgcn_mfma_f32_16x16x32_bf16(wnb[kc & 1][tt], ahh, accB[tt], 0, 0, 0);
        }
      }
    }

    // ---- epilogue: gates -> h_new (registers), y store ----
    #pragma unroll
    for (int p = 0; p < 2; ++p) {
      #pragma unroll
      for (int i = 0; i < 4; ++i) {
        const float r  = sigm(xg[0][p][i] + accA[p][i]);
        const float z  = sigm(xg[1][p][i] + accA[2 + p][i]);
        const float n  = tanh_f(xg[2][p][i] + r * (accB[p][i] + bhn_r[p][i]));
        const float hn = (1.f - z) * n + z * hreg[p][i];
        hreg[p][i] = hn;
        if (!last) {
          const int u = 32 * wid + 16 * p + 4 * bq + i;
          __builtin_nontemporal_store(hn,
              &y[((size_t)(b0 + bb) * S_ + t0c + t) * H_ + u]);
        }
      }
    }
  }

  // chunk boundary: persist h
  #pragma unroll
  for (int p = 0; p < 2; ++p)
    #pragma unroll
    for (int i = 0; i < 4; ++i) {
      const int u = 32 * wid + 16 * p + 4 * bq + i;
      hbuf[(size_t)(b0 + bb) * H_ + u] = hreg[p][i];
    }
}

// ---------------------------------------------------------------------------
// Head: LayerNorm(h_last) -> MLP 256->32 (ReLU) -> 32->1. One wave per batch.
// ---------------------------------------------------------------------------
__global__ __launch_bounds__(64) void head_kernel(
    const float* __restrict__ hlast, const float* __restrict__ lng,
    const float* __restrict__ lnb, const float* __restrict__ W1,
    const float* __restrict__ b1, const float* __restrict__ W2,
    const float* __restrict__ b2, float* __restrict__ out)
{
  const int b = blockIdx.x;
  const int lane = threadIdx.x;
  float4 v = *(const float4*)&hlast[(size_t)b * H_ + lane * 4];
  float s = v.x + v.y + v.z + v.w;
  #pragma unroll
  for (int m = 32; m > 0; m >>= 1) s += __shfl_xor(s, m, 64);
  const float mu = s * (1.f / 256.f);
  const float dx = v.x - mu, dy = v.y - mu, dz = v.z - mu, dw = v.w - mu;
  float q = dx*dx + dy*dy + dz*dz + dw*dw;
  #pragma unroll
  for (int m = 32; m > 0; m >>= 1) q += __shfl_xor(q, m, 64);
  const float rstd = rsqrtf(q * (1.f / 256.f) + 1e-5f);

  __shared__ float ln[256];
  const int i4 = lane * 4;
  ln[i4 + 0] = dx * rstd * lng[i4 + 0] + lnb[i4 + 0];
  ln[i4 + 1] = dy * rstd * lng[i4 + 1] + lnb[i4 + 1];
  ln[i4 + 2] = dz * rstd * lng[i4 + 2] + lnb[i4 + 2];
  ln[i4 + 3] = dw * rstd * lng[i4 + 3] + lnb[i4 + 3];
  __syncthreads();

  float hd = 0.f;
  if (lane < 32) {
    const float* w = W1 + (size_t)lane * H_;
    float a = 0.f;
    for (int k = 0; k < H_; ++k) a += ln[k] * w[k];
    a += b1[lane];
    hd = fmaxf(a, 0.f) * W2[lane];
  }
  #pragma unroll
  for (int m = 16; m > 0; m >>= 1) hd += __shfl_xor(hd, m, 64);
  if (lane == 0) out[b] = hd + b2[0];
}

// ---------------------------------------------------------------------------
extern "C" void kernel_launch(void* const* d_in, const int* in_sizes, int n_in,
                              void* d_out, int out_size, void* d_ws, size_t ws_size,
                              hipStream_t stream)
{
  const float* x     = (const float*)d_in[0];
  const float* W_ih0 = (const float*)d_in[1];
  const float* W_ihr = (const float*)d_in[2];
  const float* W_hh  = (const float*)d_in[3];
  const float* b_ih  = (const float*)d_in[4];
  const float* b_hh  = (const float*)d_in[5];
  const float* lng   = (const float*)d_in[6];
  const float* lnb   = (const float*)d_in[7];
  const float* W1    = (const float*)d_in[8];
  const float* b1    = (const float*)d_in[9];
  const float* W2    = (const float*)d_in[10];
  const float* b2    = (const float*)d_in[11];
  float* out = (float*)d_out;

  const size_t y_elems   = (size_t)B_ * S_ * H_;       // 134 MB
  const size_t h_elems   = (size_t)B_ * H_;
  const size_t wpk_bytes = (size_t)G3_ * H_ * 2;       // 384 KB each (bf16)

  int CH = 512;
  while (CH > 64) {
    size_t need = (y_elems + (size_t)B_ * CH * G3_ + h_elems + 768) * 4
                + 2 * wpk_bytes + 4096;
    if (need <= ws_size) break;
    CH >>= 1;
  }
  const int chsh = __builtin_ctz((unsigned)CH);

  float* y    = (float*)d_ws;
  float* gx   = y + y_elems;
  float* hbuf = gx + (size_t)B_ * CH * G3_;
  unsigned short* Whp = (unsigned short*)(hbuf + h_elems);
  unsigned short* Wlp = Whp + (size_t)G3_ * H_;
  float* bias2 = (float*)(Wlp + (size_t)G3_ * H_);

  const size_t lds_bytes = 65536 * 2 + 2 * 4096 * 2;   // 147456

  for (int l = 0; l < 3; ++l) {
    const float* Wih   = (l == 0) ? W_ih0 : (W_ihr + (size_t)(l - 1) * G3_ * H_);
    const int    K     = (l == 0) ? D_ : H_;
    const float* A     = (l == 0) ? x : y;
    const float* Whh_l = W_hh + (size_t)l * G3_ * H_;
    const float* bih_l = b_ih + (size_t)l * G3_;
    const float* bhh_l = b_hh + (size_t)l * G3_;
    const int last = (l == 2) ? 1 : 0;

    bias2_k<<<1, 768, 0, stream>>>(bih_l, bhh_l, bias2);
    pack_whh<<<dim3(48, 8), 64, 0, stream>>>(Whh_l, Whp, Wlp);

    for (int t0 = 0; t0 < S_; t0 += CH) {
      gemm_mfma<<<dim3(G3_ / 64, (B_ * CH) / 64), 256, 0, stream>>>(
          A, Wih, bias2, gx, K, chsh, t0);
      gru_scan<<<16, 512, lds_bytes, stream>>>(
          gx, Whp, Wlp, bhh_l, hbuf, y, CH, t0, last);
    }
  }

  head_kernel<<<256, 64, 0, stream>>>(hbuf, lng, lnb, W1, b1, W2, b2, out);
}